// Round 1
// 198.130 us; speedup vs baseline: 1.0587x; 1.0587x over previous
//
#include <hip/hip_runtime.h>
#include <math.h>

// x: (8, 64, 4, 128, 128) fp32; k=2, s=2, p=0 -> Ho=Wo=64, L=4096, K=4
#define NB 8
#define NG 64
#define NQ 4
#define NH 128
#define NW 128
#define NL 4096
#define EPSF 1e-8f

// ws layout: ent[NB*NG*NL] u32 monotonic-entropy keys = 8 MiB.
// Fully overwritten by fused_kernel each launch -> no memset needed.

// Fused pass: one block per (b,g), 1024 threads. Each thread owns 2 float4
// column-positions (= 4 windows): computes quaternion mags into registers,
// block-reduces the per-k fp64 sums over L, broadcasts 1/(S+eps), computes
// entropy per window, packs monotonic ent bits, and stores the two keys of
// adjacent output columns as ONE coalesced uint2 (replaces 4 atomicMax/thread:
// the 2M-op, 64-way-contended u64 atomic tournament was the only term off the
// memory/VALU rooflines).
__global__ __launch_bounds__(1024) void fused_kernel(const float4* __restrict__ x4,
                                                     unsigned int* __restrict__ ent) {
    int bg = blockIdx.x;          // b*64 + g
    int tid = threadIdx.x;

    long base4 = (long)(bg * NQ) * (NH * NW / 4);

    float mg[2][2][4];            // [pos][windowA/B][k]
    double dsum[4] = {0.0, 0.0, 0.0, 0.0};
#pragma unroll
    for (int pp = 0; pp < 2; pp++) {
        int pos = tid + pp * 1024;          // [0,2048): ho = pos>>5, wp = pos&31
        int ho = pos >> 5, wp = pos & 31;
        float sqA[4] = {0.f, 0.f, 0.f, 0.f};
        float sqB[4] = {0.f, 0.f, 0.f, 0.f};
#pragma unroll
        for (int q = 0; q < NQ; q++) {
#pragma unroll
            for (int i = 0; i < 2; i++) {
                float4 v = x4[base4 + (long)q * (NH * NW / 4) + (2 * ho + i) * (NW / 4) + wp];
                // exact np order: sequential over q, no FMA contraction
                sqA[i * 2]     = __fadd_rn(sqA[i * 2],     __fmul_rn(v.x, v.x));
                sqA[i * 2 + 1] = __fadd_rn(sqA[i * 2 + 1], __fmul_rn(v.y, v.y));
                sqB[i * 2]     = __fadd_rn(sqB[i * 2],     __fmul_rn(v.z, v.z));
                sqB[i * 2 + 1] = __fadd_rn(sqB[i * 2 + 1], __fmul_rn(v.w, v.w));
            }
        }
#pragma unroll
        for (int k = 0; k < 4; k++) {
            float mA = __fsqrt_rn(sqA[k]);
            float mB = __fsqrt_rn(sqB[k]);
            mg[pp][0][k] = mA;
            mg[pp][1][k] = mB;
            dsum[k] += (double)mA + (double)mB;
        }
    }

    // block reduction of dsum[4] (fp64, order-insensitive; proved bitwise-OK)
#pragma unroll
    for (int k = 0; k < 4; k++) {
#pragma unroll
        for (int off = 32; off; off >>= 1) dsum[k] += __shfl_xor(dsum[k], off, 64);
    }
    __shared__ double lds[16][4];
    __shared__ float rcp4s[4];
    int wave = tid >> 6, lane = tid & 63;
    if (lane == 0) {
#pragma unroll
        for (int k = 0; k < 4; k++) lds[wave][k] = dsum[k];
    }
    __syncthreads();
    if (tid < 4) {
        double s = 0.0;
        for (int w = 0; w < 16; w++) s += lds[w][tid];
        float denom = __fadd_rn((float)s, EPSF);
        rcp4s[tid] = (float)(1.0 / (double)denom);
    }
    __syncthreads();
    float r0 = rcp4s[0], r1 = rcp4s[1], r2 = rcp4s[2], r3 = rcp4s[3];

    unsigned int* erow = ent + ((unsigned)bg << 12);
#pragma unroll
    for (int pp = 0; pp < 2; pp++) {
        int pos = tid + pp * 1024;
        int ho = pos >> 5, wp = pos & 31;
        unsigned int keys[2];
#pragma unroll
        for (int w = 0; w < 2; w++) {
            float p0 = __fmul_rn(mg[pp][w][0], r0);
            float p1 = __fmul_rn(mg[pp][w][1], r1);
            float p2 = __fmul_rn(mg[pp][w][2], r2);
            float p3 = __fmul_rn(mg[pp][w][3], r3);
            float e = 0.f;
            e = __fadd_rn(e, __fmul_rn(p0, logf(__fadd_rn(p0, EPSF))));
            e = __fadd_rn(e, __fmul_rn(p1, logf(__fadd_rn(p1, EPSF))));
            e = __fadd_rn(e, __fmul_rn(p2, logf(__fadd_rn(p2, EPSF))));
            e = __fadd_rn(e, __fmul_rn(p3, logf(__fadd_rn(p3, EPSF))));
            float f = -e;
            unsigned int bits = __float_as_uint(f);
            keys[w] = (bits & 0x80000000u) ? ~bits : (bits | 0x80000000u);
        }
        int l0 = ho * 64 + 2 * wp;   // even -> 8B-aligned uint2 store, fully coalesced
        *reinterpret_cast<uint2*>(erow + l0) = make_uint2(keys[0], keys[1]);
    }
}

// Argmax + gather: one thread per (b,l,q). The 4 q-lanes of a quad split the
// 64-group scan 16 ways (coalesced column reads of the key array, L2-resident),
// reduce via two 64-bit shuffles with the exact (key<<32)|(63-g) packing of the
// old atomic tournament (strict > == torch first-max), then do the same
// perfectly coalesced float4 window store as before.
__global__ __launch_bounds__(256) void argmax_gather_kernel(const float2* __restrict__ x2,
                                                            const unsigned int* __restrict__ ent,
                                                            float4* __restrict__ out4) {
    int t = blockIdx.x * 256 + threadIdx.x;   // t = (b*4096 + l)*4 + q
    int q = t & 3;
    int l = (t >> 2) & 4095;
    int b = t >> 14;

    const unsigned int* eb = ent + ((unsigned)(b * NG + q * 16) << 12) + l;
    unsigned long long best = 0ull;
#pragma unroll
    for (int i = 0; i < 16; i++) {
        unsigned int key = eb[(long)i << 12];
        int g = q * 16 + i;
        unsigned long long cur =
            ((unsigned long long)key << 32) | (unsigned long long)(63 - g);
        if (cur > best) best = cur;   // strict >: first max (lowest g) wins ties
    }
    {
        unsigned long long o1 = __shfl_xor(best, 1, 64);
        if (o1 > best) best = o1;
        unsigned long long o2 = __shfl_xor(best, 2, 64);
        if (o2 > best) best = o2;
    }
    int g = 63 - (int)(best & 63ull);

    int ho = l >> 6, wo = l & 63;
    long base2 = (long)((b * NG + g) * NQ + q) * (NH * NW / 2);
    float2 t0 = x2[base2 + (2 * ho) * (NW / 2) + wo];
    float2 t1 = x2[base2 + (2 * ho + 1) * (NW / 2) + wo];
    out4[t] = make_float4(t0.x, t0.y, t1.x, t1.y);
}

extern "C" void kernel_launch(void* const* d_in, const int* in_sizes, int n_in,
                              void* d_out, int out_size, void* d_ws, size_t ws_size,
                              hipStream_t stream) {
    const float* x = (const float*)d_in[0];
    float* out = (float*)d_out;
    unsigned int* ent = (unsigned int*)d_ws;   // 8 MiB, fully overwritten

    // 512 blocks x 1024 threads: one block per (b,g)
    fused_kernel<<<NB * NG, 1024, 0, stream>>>((const float4*)x, ent);
    // 8*4096*4 = 131,072 threads
    argmax_gather_kernel<<<(NB * NL * NQ) / 256, 256, 0, stream>>>(
        (const float2*)x, ent, (float4*)out);
}

// Round 2
// 197.928 us; speedup vs baseline: 1.0598x; 1.0010x over previous
//
#include <hip/hip_runtime.h>
#include <math.h>

// x: (8, 64, 4, 128, 128) fp32; k=2, s=2, p=0 -> Ho=Wo=64, L=4096, K=4
#define NB 8
#define NG 64
#define NQ 4
#define NH 128
#define NW 128
#define NL 4096
#define EPSF 1e-8f

// ws layout: ent[NB*NG*NL] u32 monotonic-entropy keys = 8 MiB.
// Fully overwritten by fused_kernel each launch -> no memset needed.

// Fused pass: one block per (b,g), 1024 threads, 2 positions (4 windows) each.
// R2 change: mags go to LDS instead of registers ([w][k][pos] layout: stride-1
// across lanes -> conflict-free), and __launch_bounds__(1024,8) forces the
// <=64-VGPR budget so TWO blocks fit per CU (32 waves). Theory: fused was
// ~37us vs 21us x-read floor because 1 block/CU left the barrier+reduce+
// entropy tail with nothing to overlap. LDS: 64KiB/block x 2 blocks = 128KiB
// <= 160KiB/CU. Numerics bit-identical: same mag f32 bits round-trip LDS,
// same fp64 accumulation order.
__global__ __launch_bounds__(1024, 8) void fused_kernel(const float4* __restrict__ x4,
                                                        unsigned int* __restrict__ ent) {
    __shared__ float lmag[2][4][2048];   // [windowA/B][k][pos] = 64 KiB
    __shared__ double lds[16][4];
    __shared__ float rcp4s[4];

    int bg = blockIdx.x;          // b*64 + g
    int tid = threadIdx.x;

    long base4 = (long)(bg * NQ) * (NH * NW / 4);

    double dsum[4] = {0.0, 0.0, 0.0, 0.0};
#pragma unroll
    for (int pp = 0; pp < 2; pp++) {
        int pos = tid + pp * 1024;          // [0,2048): ho = pos>>5, wp = pos&31
        int ho = pos >> 5, wp = pos & 31;
        float sqA[4] = {0.f, 0.f, 0.f, 0.f};
        float sqB[4] = {0.f, 0.f, 0.f, 0.f};
#pragma unroll
        for (int q = 0; q < NQ; q++) {
#pragma unroll
            for (int i = 0; i < 2; i++) {
                float4 v = x4[base4 + (long)q * (NH * NW / 4) + (2 * ho + i) * (NW / 4) + wp];
                // exact np order: sequential over q, no FMA contraction
                sqA[i * 2]     = __fadd_rn(sqA[i * 2],     __fmul_rn(v.x, v.x));
                sqA[i * 2 + 1] = __fadd_rn(sqA[i * 2 + 1], __fmul_rn(v.y, v.y));
                sqB[i * 2]     = __fadd_rn(sqB[i * 2],     __fmul_rn(v.z, v.z));
                sqB[i * 2 + 1] = __fadd_rn(sqB[i * 2 + 1], __fmul_rn(v.w, v.w));
            }
        }
#pragma unroll
        for (int k = 0; k < 4; k++) {
            float mA = __fsqrt_rn(sqA[k]);
            float mB = __fsqrt_rn(sqB[k]);
            lmag[0][k][pos] = mA;
            lmag[1][k][pos] = mB;
            dsum[k] += (double)mA + (double)mB;
        }
    }

    // block reduction of dsum[4] (fp64, order-insensitive; proved bitwise-OK)
#pragma unroll
    for (int k = 0; k < 4; k++) {
#pragma unroll
        for (int off = 32; off; off >>= 1) dsum[k] += __shfl_xor(dsum[k], off, 64);
    }
    int wave = tid >> 6, lane = tid & 63;
    if (lane == 0) {
#pragma unroll
        for (int k = 0; k < 4; k++) lds[wave][k] = dsum[k];
    }
    __syncthreads();
    if (tid < 4) {
        double s = 0.0;
        for (int w = 0; w < 16; w++) s += lds[w][tid];
        float denom = __fadd_rn((float)s, EPSF);
        rcp4s[tid] = (float)(1.0 / (double)denom);
    }
    __syncthreads();
    float r0 = rcp4s[0], r1 = rcp4s[1], r2 = rcp4s[2], r3 = rcp4s[3];

    unsigned int* erow = ent + ((unsigned)bg << 12);
#pragma unroll
    for (int pp = 0; pp < 2; pp++) {
        int pos = tid + pp * 1024;
        int ho = pos >> 5, wp = pos & 31;
        unsigned int keys[2];
#pragma unroll
        for (int w = 0; w < 2; w++) {
            float p0 = __fmul_rn(lmag[w][0][pos], r0);
            float p1 = __fmul_rn(lmag[w][1][pos], r1);
            float p2 = __fmul_rn(lmag[w][2][pos], r2);
            float p3 = __fmul_rn(lmag[w][3][pos], r3);
            float e = 0.f;
            e = __fadd_rn(e, __fmul_rn(p0, logf(__fadd_rn(p0, EPSF))));
            e = __fadd_rn(e, __fmul_rn(p1, logf(__fadd_rn(p1, EPSF))));
            e = __fadd_rn(e, __fmul_rn(p2, logf(__fadd_rn(p2, EPSF))));
            e = __fadd_rn(e, __fmul_rn(p3, logf(__fadd_rn(p3, EPSF))));
            float f = -e;
            unsigned int bits = __float_as_uint(f);
            keys[w] = (bits & 0x80000000u) ? ~bits : (bits | 0x80000000u);
        }
        int l0 = ho * 64 + 2 * wp;   // even -> 8B-aligned uint2 store, fully coalesced
        *reinterpret_cast<uint2*>(erow + l0) = make_uint2(keys[0], keys[1]);
    }
}

// Argmax + gather: one thread per (b,l,q). The 4 q-lanes of a quad split the
// 64-group scan 16 ways (coalesced column reads of the key array, L3-resident),
// reduce via two 64-bit shuffles with the exact (key<<32)|(63-g) packing
// (strict > == torch first-max), then the same coalesced float4 window store.
__global__ __launch_bounds__(256) void argmax_gather_kernel(const float2* __restrict__ x2,
                                                            const unsigned int* __restrict__ ent,
                                                            float4* __restrict__ out4) {
    int t = blockIdx.x * 256 + threadIdx.x;   // t = (b*4096 + l)*4 + q
    int q = t & 3;
    int l = (t >> 2) & 4095;
    int b = t >> 14;

    const unsigned int* eb = ent + ((unsigned)(b * NG + q * 16) << 12) + l;
    unsigned long long best = 0ull;
#pragma unroll
    for (int i = 0; i < 16; i++) {
        unsigned int key = eb[(long)i << 12];
        int g = q * 16 + i;
        unsigned long long cur =
            ((unsigned long long)key << 32) | (unsigned long long)(63 - g);
        if (cur > best) best = cur;   // strict >: first max (lowest g) wins ties
    }
    {
        unsigned long long o1 = __shfl_xor(best, 1, 64);
        if (o1 > best) best = o1;
        unsigned long long o2 = __shfl_xor(best, 2, 64);
        if (o2 > best) best = o2;
    }
    int g = 63 - (int)(best & 63ull);

    int ho = l >> 6, wo = l & 63;
    long base2 = (long)((b * NG + g) * NQ + q) * (NH * NW / 2);
    float2 t0 = x2[base2 + (2 * ho) * (NW / 2) + wo];
    float2 t1 = x2[base2 + (2 * ho + 1) * (NW / 2) + wo];
    out4[t] = make_float4(t0.x, t0.y, t1.x, t1.y);
}

extern "C" void kernel_launch(void* const* d_in, const int* in_sizes, int n_in,
                              void* d_out, int out_size, void* d_ws, size_t ws_size,
                              hipStream_t stream) {
    const float* x = (const float*)d_in[0];
    float* out = (float*)d_out;
    unsigned int* ent = (unsigned int*)d_ws;   // 8 MiB, fully overwritten

    // 512 blocks x 1024 threads: one block per (b,g)
    fused_kernel<<<NB * NG, 1024, 0, stream>>>((const float4*)x, ent);
    // 8*4096*4 = 131,072 threads
    argmax_gather_kernel<<<(NB * NL * NQ) / 256, 256, 0, stream>>>(
        (const float2*)x, ent, (float4*)out);
}